// Round 4
// baseline (218.527 us; speedup 1.0000x reference)
//
#include <hip/hip_runtime.h>

#define C_DIM 1024
#define N_DIM 1024
#define O_DIM 2048
#define K_NN  20
#define KCAT  3072  // 3 * 1024: [Whi,Whi,Wlo] x [hhi,hlo,hhi]

typedef __attribute__((ext_vector_type(8))) short bf16x8;
typedef __attribute__((ext_vector_type(4))) float f32x4;

__device__ __forceinline__ unsigned short f2bf(float f) {
  unsigned u = __float_as_uint(f);
  unsigned r = (u + 0x7fffu + ((u >> 16) & 1u)) >> 16;  // RNE
  return (unsigned short)r;
}
__device__ __forceinline__ float bf2f(unsigned short h) {
  return __uint_as_float((unsigned)h << 16);
}

#define GLOAD16(gp, lp)                                                       \
  __builtin_amdgcn_global_load_lds(                                           \
      (const __attribute__((address_space(1))) unsigned int*)(uintptr_t)(gp), \
      (__attribute__((address_space(3))) unsigned int*)(uintptr_t)(lp), 16,   \
      0, 0)

// ---------------------------------------------------------------------------
// Column squared-norms, fp64 sequential (error ~1e-13, can't flip rankings).
// ---------------------------------------------------------------------------
__global__ __launch_bounds__(256) void norms_kernel(
    const float* __restrict__ x, double* __restrict__ s_d) {
  int j = blockIdx.x * 256 + threadIdx.x;
  double acc = 0.0;
#pragma unroll 8
  for (int c = 0; c < C_DIM; ++c) {
    float v = x[(size_t)c * N_DIM + j];
    acc = fma((double)v, (double)v, acc);
  }
  s_d[j] = acc;
}

// ---------------------------------------------------------------------------
// fp32 K-major GEMM for dot = x^T x, 64x64 tile, split-K=4, SYMMETRIC:
// only by<=bx tiles computed; mirror-stored. Bitwise == full version.
// ---------------------------------------------------------------------------
template <int KZ>
__global__ __launch_bounds__(256) void gemm64_sym(
    const float* __restrict__ A, float* __restrict__ P) {
  int bx = blockIdx.x, by = blockIdx.y;
  if (by > bx) return;  // upper triangle only
  __shared__ float Al[16][64];
  __shared__ float Bl[16][64];
  int t = threadIdx.x;
  int tx = t & 15, ty = t >> 4;
  int m0 = by * 64, n0 = bx * 64;
  int z = blockIdx.z;
  int kk = t >> 4, c4 = (t & 15) * 4;
  float acc[4][4] = {};
  for (int k0 = z * KZ; k0 < (z + 1) * KZ; k0 += 16) {
    float4 av = *(const float4*)&A[(size_t)(k0 + kk) * N_DIM + m0 + c4];
    float4 bv = *(const float4*)&A[(size_t)(k0 + kk) * N_DIM + n0 + c4];
    __syncthreads();
    *(float4*)&Al[kk][c4] = av;
    *(float4*)&Bl[kk][c4] = bv;
    __syncthreads();
#pragma unroll
    for (int q = 0; q < 16; ++q) {
      float4 a = *(const float4*)&Al[q][ty * 4];
      float4 b = *(const float4*)&Bl[q][tx * 4];
      float am[4] = {a.x, a.y, a.z, a.w};
      float bn[4] = {b.x, b.y, b.z, b.w};
#pragma unroll
      for (int i = 0; i < 4; ++i)
#pragma unroll
        for (int j = 0; j < 4; ++j)
          acc[i][j] = fmaf(am[i], bn[j], acc[i][j]);
    }
  }
#pragma unroll
  for (int i = 0; i < 4; ++i) {
    float4 v = make_float4(acc[i][0], acc[i][1], acc[i][2], acc[i][3]);
    *(float4*)&P[((size_t)z * N_DIM + m0 + ty * 4 + i) * N_DIM + n0 + tx * 4] = v;
  }
  if (bx != by) {  // mirror (products commutative -> bitwise identical)
#pragma unroll
    for (int j = 0; j < 4; ++j) {
      float4 v = make_float4(acc[0][j], acc[1][j], acc[2][j], acc[3][j]);
      *(float4*)&P[((size_t)z * N_DIM + n0 + tx * 4 + j) * N_DIM + m0 + ty * 4] = v;
    }
  }
}

// ---------------------------------------------------------------------------
// Top-20 of d_j = 2*sum_z P[z][i][j] - s_d[j]; fp64; tie -> lowest index.
// ---------------------------------------------------------------------------
__global__ __launch_bounds__(64) void topk_kernel(
    const float* __restrict__ P, const double* __restrict__ s_d,
    int* __restrict__ idxo) {
  int i = blockIdx.x;
  int l = threadIdx.x;
  double d[16];
#pragma unroll
  for (int q = 0; q < 16; ++q) {
    int j = q * 64 + l;
    double s = 0.0;
#pragma unroll
    for (int z = 0; z < 4; ++z)
      s += (double)P[((size_t)z * N_DIM + i) * N_DIM + j];
    d[q] = 2.0 * s - s_d[j];
  }
  for (int r = 0; r < K_NN; ++r) {
    double bv = -1e300;
    int bj = N_DIM;
#pragma unroll
    for (int q = 0; q < 16; ++q) {
      int j = q * 64 + l;
      if (d[q] > bv) { bv = d[q]; bj = j; }
    }
#pragma unroll
    for (int off = 32; off; off >>= 1) {
      double ov = __shfl_xor(bv, off);
      int oj = __shfl_xor(bj, off);
      if (ov > bv || (ov == bv && oj < bj)) { bv = ov; bj = oj; }
    }
    if (l == 0) idxo[i * K_NN + r] = bj;
    int kq = bj >> 6, kl = bj & 63;
    if (l == kl) {
#pragma unroll
      for (int q = 0; q < 16; ++q)
        if (q == kq) d[q] = -1e300;
    }
  }
}

// ---------------------------------------------------------------------------
// Fused transpose: x,eps (C,N) -> xT (N,C) and gT[n][c] = (1+eps)*x.
// ---------------------------------------------------------------------------
__global__ __launch_bounds__(256) void fused_transpose(
    const float* __restrict__ x, const float* __restrict__ eps,
    float* __restrict__ xT, float* __restrict__ gT) {
  __shared__ float tx_[32][33], tg_[32][33];
  int bx = blockIdx.x * 32, by = blockIdx.y * 32;
  int c = threadIdx.x & 31, r = threadIdx.x >> 5;
#pragma unroll
  for (int rr = 0; rr < 4; ++rr) {
    int row = by + r + 8 * rr;
    float xv = x[(size_t)row * N_DIM + bx + c];
    float ev = eps[(size_t)row * N_DIM + bx + c];
    tx_[r + 8 * rr][c] = xv;
    tg_[r + 8 * rr][c] = (1.f + ev) * xv;
  }
  __syncthreads();
#pragma unroll
  for (int rr = 0; rr < 4; ++rr) {
    xT[(size_t)(bx + r + 8 * rr) * C_DIM + by + c] = tx_[c][r + 8 * rr];
    gT[(size_t)(bx + r + 8 * rr) * C_DIM + by + c] = tg_[c][r + 8 * rr];
  }
}

// ---------------------------------------------------------------------------
// Gather + eps residual -> Bcat directly (bf16 hi/lo, fragment-permuted,
// 8-chunk XOR-swizzled 128B slabs). One block per n, 128 threads.
// thread t: window g = t>>2 (0..31), h = t&3; covers c = 32g+4h+{0..3,16..19}.
// slab s = g>>1, wk = g&1, phys chunk pc = (4*wk+h) ^ (n&7).
// segs: 0 = hi, 1 = lo, 2 = hi.
// ---------------------------------------------------------------------------
__global__ __launch_bounds__(128) void gather_bcat(
    const float* __restrict__ xT, const float* __restrict__ gT,
    const int* __restrict__ idxo, unsigned short* __restrict__ Bcat) {
  int n = blockIdx.x;
  int t = threadIdx.x;
  int g = t >> 2, h = t & 3;
  int c1 = g * 32 + h * 4;
  int nb[K_NN];
#pragma unroll
  for (int k = 0; k < K_NN; ++k) nb[k] = idxo[n * K_NN + k];
  float4 s1 = *(const float4*)&gT[(size_t)n * C_DIM + c1];
  float4 s2 = *(const float4*)&gT[(size_t)n * C_DIM + c1 + 16];
#pragma unroll
  for (int k = 0; k < K_NN; ++k) {
    const float* rp = &xT[(size_t)nb[k] * C_DIM];
    float4 v1 = *(const float4*)&rp[c1];
    float4 v2 = *(const float4*)&rp[c1 + 16];
    s1.x += v1.x; s1.y += v1.y; s1.z += v1.z; s1.w += v1.w;
    s2.x += v2.x; s2.y += v2.y; s2.z += v2.z; s2.w += v2.w;
  }
  float vv[8] = {s1.x, s1.y, s1.z, s1.w, s2.x, s2.y, s2.z, s2.w};
  unsigned hi[8], lo[8];
#pragma unroll
  for (int i = 0; i < 8; ++i) {
    unsigned short hb = f2bf(vv[i]);
    hi[i] = hb;
    lo[i] = f2bf(vv[i] - bf2f(hb));
  }
  uint4 ph, pl;
  ph.x = hi[0] | (hi[1] << 16); ph.y = hi[2] | (hi[3] << 16);
  ph.z = hi[4] | (hi[5] << 16); ph.w = hi[6] | (hi[7] << 16);
  pl.x = lo[0] | (lo[1] << 16); pl.y = lo[2] | (lo[3] << 16);
  pl.z = lo[4] | (lo[5] << 16); pl.w = lo[6] | (lo[7] << 16);
  int s = g >> 1;
  int pc = ((g & 1) * 4 + h) ^ (n & 7);
  unsigned short* row = Bcat + (size_t)n * KCAT;
  *(uint4*)(row + s * 64 + pc * 8) = ph;
  *(uint4*)(row + 1024 + s * 64 + pc * 8) = pl;
  *(uint4*)(row + 2048 + s * 64 + pc * 8) = ph;
}

// ---------------------------------------------------------------------------
// W (O,C) -> Acat: segs hi, hi, lo; same slab/chunk permutation, key = m&7.
// ---------------------------------------------------------------------------
__global__ __launch_bounds__(256) void conv_w(
    const float* __restrict__ W, unsigned short* __restrict__ Acat) {
  int id = blockIdx.x * 256 + threadIdx.x;  // 0 .. 2048*128-1
  int m = id >> 7;
  int gh = id & 127;
  int g = gh >> 2, h = gh & 3;
  int c1 = g * 32 + h * 4;
  const float* wp = &W[(size_t)m * C_DIM];
  float4 v1 = *(const float4*)&wp[c1];
  float4 v2 = *(const float4*)&wp[c1 + 16];
  float vv[8] = {v1.x, v1.y, v1.z, v1.w, v2.x, v2.y, v2.z, v2.w};
  unsigned hi[8], lo[8];
#pragma unroll
  for (int i = 0; i < 8; ++i) {
    unsigned short hb = f2bf(vv[i]);
    hi[i] = hb;
    lo[i] = f2bf(vv[i] - bf2f(hb));
  }
  uint4 ph, pl;
  ph.x = hi[0] | (hi[1] << 16); ph.y = hi[2] | (hi[3] << 16);
  ph.z = hi[4] | (hi[5] << 16); ph.w = hi[6] | (hi[7] << 16);
  pl.x = lo[0] | (lo[1] << 16); pl.y = lo[2] | (lo[3] << 16);
  pl.z = lo[4] | (lo[5] << 16); pl.w = lo[6] | (lo[7] << 16);
  int s = g >> 1;
  int pc = ((g & 1) * 4 + h) ^ (m & 7);
  unsigned short* row = Acat + (size_t)m * KCAT;
  *(uint4*)(row + s * 64 + pc * 8) = ph;
  *(uint4*)(row + 1024 + s * 64 + pc * 8) = ph;
  *(uint4*)(row + 2048 + s * 64 + pc * 8) = pl;
}

// ---------------------------------------------------------------------------
// bf16 MFMA GEMM: out (2048 x 1024) = Acat (2048 x 3072) x Bcat^T (1024 x 3072)
// 128x64 tile, 8 waves (4m x 2n, wave = 32x32), BK=64, dual-buffered LDS
// prefetch, 8-chunk XOR swizzle (2-way LDS reads = free), XCD-aware swizzle.
// ---------------------------------------------------------------------------
__global__ __launch_bounds__(512) void mfma_gemm(
    const unsigned short* __restrict__ Acat,
    const unsigned short* __restrict__ Bcat, float* __restrict__ out) {
  __shared__ unsigned short Alds[2][8192];  // [buf][128 rows x 64 k] 16KB each
  __shared__ unsigned short Blds[2][4096];  // [buf][ 64 rows x 64 k]  8KB each
  int t = threadIdx.x;
  int w = t >> 6, l = t & 63;
  int b = blockIdx.x;
  int xcd = b & 7, jb = b >> 3;
  int bx = xcd * 2 + (jb & 1);  // n-tile: 2 B-panels per XCD (L2-resident)
  int by = jb >> 1;             // m-tile
  int m0 = by * 128, n0 = bx * 64;
  int wr = w >> 1, wc = w & 1;
  int h = l >> 4, c16 = l & 15;
  int s8 = c16 & 7;

  // staging: A = 1024 chunks (t, t+512), B = 512 chunks (t). 16B each.
  const char* gA = (const char*)Acat + (size_t)(m0 + (t >> 3)) * (KCAT * 2) +
                   (t & 7) * 16;
  const char* gB = (const char*)Bcat + (size_t)(n0 + (t >> 3)) * (KCAT * 2) +
                   (t & 7) * 16;

  // frag LDS offsets (ushort units): row*64 + ((4*wk+h)^s8)*8
  int ao00 = (wr * 32 + 0 + c16) * 64 + (((0 + h) ^ s8) * 8);
  int ao01 = (wr * 32 + 0 + c16) * 64 + (((4 + h) ^ s8) * 8);
  int ao10 = (wr * 32 + 16 + c16) * 64 + (((0 + h) ^ s8) * 8);
  int ao11 = (wr * 32 + 16 + c16) * 64 + (((4 + h) ^ s8) * 8);
  int bo00 = (wc * 32 + 0 + c16) * 64 + (((0 + h) ^ s8) * 8);
  int bo01 = (wc * 32 + 0 + c16) * 64 + (((4 + h) ^ s8) * 8);
  int bo10 = (wc * 32 + 16 + c16) * 64 + (((0 + h) ^ s8) * 8);
  int bo11 = (wc * 32 + 16 + c16) * 64 + (((4 + h) ^ s8) * 8);

  f32x4 acc00 = {}, acc01 = {}, acc10 = {}, acc11 = {};

#define STAGE(buf, it)                                                    \
  {                                                                       \
    const char* ga = gA + (size_t)(it) * 128;                             \
    const char* gb = gB + (size_t)(it) * 128;                             \
    GLOAD16(ga, (char*)&Alds[buf][0] + t * 16);                           \
    GLOAD16(ga + (size_t)64 * (KCAT * 2),                                 \
            (char*)&Alds[buf][0] + 8192 + t * 16);                        \
    GLOAD16(gb, (char*)&Blds[buf][0] + t * 16);                           \
  }

  STAGE(0, 0);
  __syncthreads();
  for (int it = 0; it < KCAT / 64; ++it) {
    int cur = it & 1;
    if (it + 1 < KCAT / 64) STAGE(cur ^ 1, it + 1);  // prefetch next slab
    const unsigned short* Ab = &Alds[cur][0];
    const unsigned short* Bb = &Blds[cur][0];
    bf16x8 a00 = *(const bf16x8*)(Ab + ao00);
    bf16x8 a10 = *(const bf16x8*)(Ab + ao10);
    bf16x8 b00 = *(const bf16x8*)(Bb + bo00);
    bf16x8 b10 = *(const bf16x8*)(Bb + bo10);
    acc00 = __builtin_amdgcn_mfma_f32_16x16x32_bf16(a00, b00, acc00, 0, 0, 0);
    acc01 = __builtin_amdgcn_mfma_f32_16x16x32_bf16(a00, b10, acc01, 0, 0, 0);
    acc10 = __builtin_amdgcn_mfma_f32_16x16x32_bf16(a10, b00, acc10, 0, 0, 0);
    acc11 = __builtin_amdgcn_mfma_f32_16x16x32_bf16(a10, b10, acc11, 0, 0, 0);
    bf16x8 a01 = *(const bf16x8*)(Ab + ao01);
    bf16x8 a11 = *(const bf16x8*)(Ab + ao11);
    bf16x8 b01 = *(const bf16x8*)(Bb + bo01);
    bf16x8 b11 = *(const bf16x8*)(Bb + bo11);
    acc00 = __builtin_amdgcn_mfma_f32_16x16x32_bf16(a01, b01, acc00, 0, 0, 0);
    acc01 = __builtin_amdgcn_mfma_f32_16x16x32_bf16(a01, b11, acc01, 0, 0, 0);
    acc10 = __builtin_amdgcn_mfma_f32_16x16x32_bf16(a11, b01, acc10, 0, 0, 0);
    acc11 = __builtin_amdgcn_mfma_f32_16x16x32_bf16(a11, b11, acc11, 0, 0, 0);
    __syncthreads();  // drains vmcnt (prefetch landed) + all waves done
  }
  // C/D: col = lane&15, row = (lane>>4)*4 + reg
#define STORE_FRAG(av, mi, ni)                                     \
  {                                                                \
    int rb = m0 + wr * 32 + (mi) * 16 + h * 4;                     \
    int col = n0 + wc * 32 + (ni) * 16 + c16;                      \
    out[(size_t)(rb + 0) * N_DIM + col] = av[0];                   \
    out[(size_t)(rb + 1) * N_DIM + col] = av[1];                   \
    out[(size_t)(rb + 2) * N_DIM + col] = av[2];                   \
    out[(size_t)(rb + 3) * N_DIM + col] = av[3];                   \
  }
  STORE_FRAG(acc00, 0, 0)
  STORE_FRAG(acc01, 0, 1)
  STORE_FRAG(acc10, 1, 0)
  STORE_FRAG(acc11, 1, 1)
#undef STORE_FRAG
#undef STAGE
}

// ---------------------------------------------------------------------------
// Launch
// ---------------------------------------------------------------------------
extern "C" void kernel_launch(void* const* d_in, const int* in_sizes, int n_in,
                              void* d_out, int out_size, void* d_ws,
                              size_t ws_size, hipStream_t stream) {
  const float* x = (const float*)d_in[0];    // (C, N)
  const float* W = (const float*)d_in[1];    // (O, C)
  const float* eps = (const float*)d_in[2];  // (C, N)
  float* out = (float*)d_out;                // (O, N)
  char* ws = (char*)d_ws;

  double* s_d = (double*)(ws + 0);                          //   8 KB
  int* idxo = (int*)(ws + 8192);                            //  80 KB
  float* xT = (float*)(ws + 131072);                        //   4 MB
  float* gT = (float*)(ws + 4325376);                       //   4 MB
  float* partials = (float*)(ws + 8519680);                 //  16 MB
  unsigned short* Acat = (unsigned short*)(ws + 25296896);  //  12 MB
  unsigned short* Bcat = (unsigned short*)(ws + 37879808);  //   6 MB

  norms_kernel<<<4, 256, 0, stream>>>(x, s_d);

  // dot products: fp32, symmetric, split-K=4
  gemm64_sym<256><<<dim3(16, 16, 4), 256, 0, stream>>>(x, partials);

  // independent prep (fills stream while dist results settle)
  fused_transpose<<<dim3(32, 32), 256, 0, stream>>>(x, eps, xT, gT);
  conv_w<<<1024, 256, 0, stream>>>(W, Acat);

  topk_kernel<<<N_DIM, 64, 0, stream>>>(partials, s_d, idxo);

  gather_bcat<<<N_DIM, 128, 0, stream>>>(xT, gT, idxo, Bcat);

  // out = W @ h via bf16 MFMA, grid 256 (XCD-swizzled internally)
  mfma_gemm<<<256, 512, 0, stream>>>(Acat, Bcat, out);
}

// Round 5
// 174.109 us; speedup vs baseline: 1.2551x; 1.2551x over previous
//
#include <hip/hip_runtime.h>

#define C_DIM 1024
#define N_DIM 1024
#define O_DIM 2048
#define K_NN  20
#define KCAT  3072  // 3 * 1024: [Whi,Whi,Wlo] x [hhi,hlo,hhi]
#define NZ    8     // dist GEMM split-K factor

typedef __attribute__((ext_vector_type(8))) short bf16x8;
typedef __attribute__((ext_vector_type(4))) float f32x4;

__device__ __forceinline__ unsigned short f2bf(float f) {
  unsigned u = __float_as_uint(f);
  unsigned r = (u + 0x7fffu + ((u >> 16) & 1u)) >> 16;  // RNE
  return (unsigned short)r;
}
__device__ __forceinline__ float bf2f(unsigned short h) {
  return __uint_as_float((unsigned)h << 16);
}

#define GLOAD16(gp, lp)                                                       \
  __builtin_amdgcn_global_load_lds(                                           \
      (const __attribute__((address_space(1))) unsigned int*)(uintptr_t)(gp), \
      (__attribute__((address_space(3))) unsigned int*)(uintptr_t)(lp), 16,   \
      0, 0)

// ---------------------------------------------------------------------------
// Column squared-norm partials, fp64. grid (4 j-blocks, 64 c-blocks):
// 256 blocks (vs round-4's 4 -> was 76us latency-bound at 0.17% occupancy).
// Summation order preserved (ascending c within partial, partials ascending).
// ---------------------------------------------------------------------------
__global__ __launch_bounds__(256) void norms_partial_kernel(
    const float* __restrict__ x, double* __restrict__ part) {
  int j = blockIdx.x * 256 + threadIdx.x;
  int cb = blockIdx.y;  // 0..63
  double acc = 0.0;
  int c0 = cb * 16;
#pragma unroll
  for (int c = c0; c < c0 + 16; ++c) {
    float v = x[(size_t)c * N_DIM + j];
    acc = fma((double)v, (double)v, acc);
  }
  part[(size_t)cb * N_DIM + j] = acc;
}

__global__ __launch_bounds__(256) void norms_reduce_kernel(
    const double* __restrict__ part, double* __restrict__ s_d) {
  int j = blockIdx.x * 256 + threadIdx.x;
  double a = 0.0;
#pragma unroll
  for (int cb = 0; cb < 64; ++cb) a += part[(size_t)cb * N_DIM + j];
  s_d[j] = a;
}

// ---------------------------------------------------------------------------
// fp32 K-major GEMM for dot = x^T x, 64x64 tile, split-K=NZ, SYMMETRIC:
// only by<=bx tiles computed; mirror-stored (products commutative -> bitwise
// identical). grid (16,16,NZ): 136*NZ working blocks.
// ---------------------------------------------------------------------------
template <int KZ>
__global__ __launch_bounds__(256) void gemm64_sym(
    const float* __restrict__ A, float* __restrict__ P) {
  int bx = blockIdx.x, by = blockIdx.y;
  if (by > bx) return;  // upper triangle only
  __shared__ float Al[16][64];
  __shared__ float Bl[16][64];
  int t = threadIdx.x;
  int tx = t & 15, ty = t >> 4;
  int m0 = by * 64, n0 = bx * 64;
  int z = blockIdx.z;
  int kk = t >> 4, c4 = (t & 15) * 4;
  float acc[4][4] = {};
  for (int k0 = z * KZ; k0 < (z + 1) * KZ; k0 += 16) {
    float4 av = *(const float4*)&A[(size_t)(k0 + kk) * N_DIM + m0 + c4];
    float4 bv = *(const float4*)&A[(size_t)(k0 + kk) * N_DIM + n0 + c4];
    __syncthreads();
    *(float4*)&Al[kk][c4] = av;
    *(float4*)&Bl[kk][c4] = bv;
    __syncthreads();
#pragma unroll
    for (int q = 0; q < 16; ++q) {
      float4 a = *(const float4*)&Al[q][ty * 4];
      float4 b = *(const float4*)&Bl[q][tx * 4];
      float am[4] = {a.x, a.y, a.z, a.w};
      float bn[4] = {b.x, b.y, b.z, b.w};
#pragma unroll
      for (int i = 0; i < 4; ++i)
#pragma unroll
        for (int j = 0; j < 4; ++j)
          acc[i][j] = fmaf(am[i], bn[j], acc[i][j]);
    }
  }
#pragma unroll
  for (int i = 0; i < 4; ++i) {
    float4 v = make_float4(acc[i][0], acc[i][1], acc[i][2], acc[i][3]);
    *(float4*)&P[((size_t)z * N_DIM + m0 + ty * 4 + i) * N_DIM + n0 + tx * 4] = v;
  }
  if (bx != by) {  // mirror
#pragma unroll
    for (int j = 0; j < 4; ++j) {
      float4 v = make_float4(acc[0][j], acc[1][j], acc[2][j], acc[3][j]);
      *(float4*)&P[((size_t)z * N_DIM + n0 + tx * 4 + j) * N_DIM + m0 + ty * 4] = v;
    }
  }
}

// ---------------------------------------------------------------------------
// Top-20 of d_j = 2*sum_z P[z][i][j] - s_d[j]; fp64; tie -> lowest index.
// ---------------------------------------------------------------------------
__global__ __launch_bounds__(64) void topk_kernel(
    const float* __restrict__ P, const double* __restrict__ s_d,
    int* __restrict__ idxo) {
  int i = blockIdx.x;
  int l = threadIdx.x;
  double d[16];
#pragma unroll
  for (int q = 0; q < 16; ++q) {
    int j = q * 64 + l;
    double s = 0.0;
#pragma unroll
    for (int z = 0; z < NZ; ++z)
      s += (double)P[((size_t)z * N_DIM + i) * N_DIM + j];
    d[q] = 2.0 * s - s_d[j];
  }
  for (int r = 0; r < K_NN; ++r) {
    double bv = -1e300;
    int bj = N_DIM;
#pragma unroll
    for (int q = 0; q < 16; ++q) {
      int j = q * 64 + l;
      if (d[q] > bv) { bv = d[q]; bj = j; }
    }
#pragma unroll
    for (int off = 32; off; off >>= 1) {
      double ov = __shfl_xor(bv, off);
      int oj = __shfl_xor(bj, off);
      if (ov > bv || (ov == bv && oj < bj)) { bv = ov; bj = oj; }
    }
    if (l == 0) idxo[i * K_NN + r] = bj;
    int kq = bj >> 6, kl = bj & 63;
    if (l == kl) {
#pragma unroll
      for (int q = 0; q < 16; ++q)
        if (q == kq) d[q] = -1e300;
    }
  }
}

// ---------------------------------------------------------------------------
// Fused transpose: x,eps (C,N) -> xT (N,C) and gT[n][c] = (1+eps)*x.
// ---------------------------------------------------------------------------
__global__ __launch_bounds__(256) void fused_transpose(
    const float* __restrict__ x, const float* __restrict__ eps,
    float* __restrict__ xT, float* __restrict__ gT) {
  __shared__ float tx_[32][33], tg_[32][33];
  int bx = blockIdx.x * 32, by = blockIdx.y * 32;
  int c = threadIdx.x & 31, r = threadIdx.x >> 5;
#pragma unroll
  for (int rr = 0; rr < 4; ++rr) {
    int row = by + r + 8 * rr;
    float xv = x[(size_t)row * N_DIM + bx + c];
    float ev = eps[(size_t)row * N_DIM + bx + c];
    tx_[r + 8 * rr][c] = xv;
    tg_[r + 8 * rr][c] = (1.f + ev) * xv;
  }
  __syncthreads();
#pragma unroll
  for (int rr = 0; rr < 4; ++rr) {
    xT[(size_t)(bx + r + 8 * rr) * C_DIM + by + c] = tx_[c][r + 8 * rr];
    gT[(size_t)(bx + r + 8 * rr) * C_DIM + by + c] = tg_[c][r + 8 * rr];
  }
}

// ---------------------------------------------------------------------------
// Gather + eps residual -> Bcat directly (bf16 hi/lo, fragment-permuted,
// 8-chunk XOR-swizzled 128B slabs). One block per n, 128 threads.
// ---------------------------------------------------------------------------
__global__ __launch_bounds__(128) void gather_bcat(
    const float* __restrict__ xT, const float* __restrict__ gT,
    const int* __restrict__ idxo, unsigned short* __restrict__ Bcat) {
  int n = blockIdx.x;
  int t = threadIdx.x;
  int g = t >> 2, h = t & 3;
  int c1 = g * 32 + h * 4;
  int nb[K_NN];
#pragma unroll
  for (int k = 0; k < K_NN; ++k) nb[k] = idxo[n * K_NN + k];
  float4 s1 = *(const float4*)&gT[(size_t)n * C_DIM + c1];
  float4 s2 = *(const float4*)&gT[(size_t)n * C_DIM + c1 + 16];
#pragma unroll
  for (int k = 0; k < K_NN; ++k) {
    const float* rp = &xT[(size_t)nb[k] * C_DIM];
    float4 v1 = *(const float4*)&rp[c1];
    float4 v2 = *(const float4*)&rp[c1 + 16];
    s1.x += v1.x; s1.y += v1.y; s1.z += v1.z; s1.w += v1.w;
    s2.x += v2.x; s2.y += v2.y; s2.z += v2.z; s2.w += v2.w;
  }
  float vv[8] = {s1.x, s1.y, s1.z, s1.w, s2.x, s2.y, s2.z, s2.w};
  unsigned hi[8], lo[8];
#pragma unroll
  for (int i = 0; i < 8; ++i) {
    unsigned short hb = f2bf(vv[i]);
    hi[i] = hb;
    lo[i] = f2bf(vv[i] - bf2f(hb));
  }
  uint4 ph, pl;
  ph.x = hi[0] | (hi[1] << 16); ph.y = hi[2] | (hi[3] << 16);
  ph.z = hi[4] | (hi[5] << 16); ph.w = hi[6] | (hi[7] << 16);
  pl.x = lo[0] | (lo[1] << 16); pl.y = lo[2] | (lo[3] << 16);
  pl.z = lo[4] | (lo[5] << 16); pl.w = lo[6] | (lo[7] << 16);
  int s = g >> 1;
  int pc = ((g & 1) * 4 + h) ^ (n & 7);
  unsigned short* row = Bcat + (size_t)n * KCAT;
  *(uint4*)(row + s * 64 + pc * 8) = ph;
  *(uint4*)(row + 1024 + s * 64 + pc * 8) = pl;
  *(uint4*)(row + 2048 + s * 64 + pc * 8) = ph;
}

// ---------------------------------------------------------------------------
// W (O,C) -> Acat: segs hi, hi, lo; same slab/chunk permutation, key = m&7.
// ---------------------------------------------------------------------------
__global__ __launch_bounds__(256) void conv_w(
    const float* __restrict__ W, unsigned short* __restrict__ Acat) {
  int id = blockIdx.x * 256 + threadIdx.x;  // 0 .. 2048*128-1
  int m = id >> 7;
  int gh = id & 127;
  int g = gh >> 2, h = gh & 3;
  int c1 = g * 32 + h * 4;
  const float* wp = &W[(size_t)m * C_DIM];
  float4 v1 = *(const float4*)&wp[c1];
  float4 v2 = *(const float4*)&wp[c1 + 16];
  float vv[8] = {v1.x, v1.y, v1.z, v1.w, v2.x, v2.y, v2.z, v2.w};
  unsigned hi[8], lo[8];
#pragma unroll
  for (int i = 0; i < 8; ++i) {
    unsigned short hb = f2bf(vv[i]);
    hi[i] = hb;
    lo[i] = f2bf(vv[i] - bf2f(hb));
  }
  uint4 ph, pl;
  ph.x = hi[0] | (hi[1] << 16); ph.y = hi[2] | (hi[3] << 16);
  ph.z = hi[4] | (hi[5] << 16); ph.w = hi[6] | (hi[7] << 16);
  pl.x = lo[0] | (lo[1] << 16); pl.y = lo[2] | (lo[3] << 16);
  pl.z = lo[4] | (lo[5] << 16); pl.w = lo[6] | (lo[7] << 16);
  int s = g >> 1;
  int pc = ((g & 1) * 4 + h) ^ (m & 7);
  unsigned short* row = Acat + (size_t)m * KCAT;
  *(uint4*)(row + s * 64 + pc * 8) = ph;
  *(uint4*)(row + 1024 + s * 64 + pc * 8) = ph;
  *(uint4*)(row + 2048 + s * 64 + pc * 8) = pl;
}

// ---------------------------------------------------------------------------
// bf16 MFMA GEMM: out (2048 x 1024) = Acat (2048 x 3072) x Bcat^T (1024 x 3072)
// 128x64 tile, 8 waves (4m x 2n, wave = 32x32), BK=64, dual-buffered LDS
// prefetch, 8-chunk XOR swizzle (2-way LDS reads = free), XCD-aware swizzle.
// ---------------------------------------------------------------------------
__global__ __launch_bounds__(512) void mfma_gemm(
    const unsigned short* __restrict__ Acat,
    const unsigned short* __restrict__ Bcat, float* __restrict__ out) {
  __shared__ unsigned short Alds[2][8192];  // [buf][128 rows x 64 k] 16KB each
  __shared__ unsigned short Blds[2][4096];  // [buf][ 64 rows x 64 k]  8KB each
  int t = threadIdx.x;
  int w = t >> 6, l = t & 63;
  int b = blockIdx.x;
  int xcd = b & 7, jb = b >> 3;
  int bx = xcd * 2 + (jb & 1);  // n-tile: 2 B-panels per XCD (L2-resident)
  int by = jb >> 1;             // m-tile
  int m0 = by * 128, n0 = bx * 64;
  int wr = w >> 1, wc = w & 1;
  int h = l >> 4, c16 = l & 15;
  int s8 = c16 & 7;

  const char* gA = (const char*)Acat + (size_t)(m0 + (t >> 3)) * (KCAT * 2) +
                   (t & 7) * 16;
  const char* gB = (const char*)Bcat + (size_t)(n0 + (t >> 3)) * (KCAT * 2) +
                   (t & 7) * 16;

  int ao00 = (wr * 32 + 0 + c16) * 64 + (((0 + h) ^ s8) * 8);
  int ao01 = (wr * 32 + 0 + c16) * 64 + (((4 + h) ^ s8) * 8);
  int ao10 = (wr * 32 + 16 + c16) * 64 + (((0 + h) ^ s8) * 8);
  int ao11 = (wr * 32 + 16 + c16) * 64 + (((4 + h) ^ s8) * 8);
  int bo00 = (wc * 32 + 0 + c16) * 64 + (((0 + h) ^ s8) * 8);
  int bo01 = (wc * 32 + 0 + c16) * 64 + (((4 + h) ^ s8) * 8);
  int bo10 = (wc * 32 + 16 + c16) * 64 + (((0 + h) ^ s8) * 8);
  int bo11 = (wc * 32 + 16 + c16) * 64 + (((4 + h) ^ s8) * 8);

  f32x4 acc00 = {}, acc01 = {}, acc10 = {}, acc11 = {};

#define STAGE(buf, it)                                                    \
  {                                                                       \
    const char* ga = gA + (size_t)(it) * 128;                             \
    const char* gb = gB + (size_t)(it) * 128;                             \
    GLOAD16(ga, (char*)&Alds[buf][0] + t * 16);                           \
    GLOAD16(ga + (size_t)64 * (KCAT * 2),                                 \
            (char*)&Alds[buf][0] + 8192 + t * 16);                        \
    GLOAD16(gb, (char*)&Blds[buf][0] + t * 16);                           \
  }

  STAGE(0, 0);
  __syncthreads();
  for (int it = 0; it < KCAT / 64; ++it) {
    int cur = it & 1;
    if (it + 1 < KCAT / 64) STAGE(cur ^ 1, it + 1);  // prefetch next slab
    const unsigned short* Ab = &Alds[cur][0];
    const unsigned short* Bb = &Blds[cur][0];
    bf16x8 a00 = *(const bf16x8*)(Ab + ao00);
    bf16x8 a10 = *(const bf16x8*)(Ab + ao10);
    bf16x8 b00 = *(const bf16x8*)(Bb + bo00);
    bf16x8 b10 = *(const bf16x8*)(Bb + bo10);
    acc00 = __builtin_amdgcn_mfma_f32_16x16x32_bf16(a00, b00, acc00, 0, 0, 0);
    acc01 = __builtin_amdgcn_mfma_f32_16x16x32_bf16(a00, b10, acc01, 0, 0, 0);
    acc10 = __builtin_amdgcn_mfma_f32_16x16x32_bf16(a10, b00, acc10, 0, 0, 0);
    acc11 = __builtin_amdgcn_mfma_f32_16x16x32_bf16(a10, b10, acc11, 0, 0, 0);
    bf16x8 a01 = *(const bf16x8*)(Ab + ao01);
    bf16x8 a11 = *(const bf16x8*)(Ab + ao11);
    bf16x8 b01 = *(const bf16x8*)(Bb + bo01);
    bf16x8 b11 = *(const bf16x8*)(Bb + bo11);
    acc00 = __builtin_amdgcn_mfma_f32_16x16x32_bf16(a01, b01, acc00, 0, 0, 0);
    acc01 = __builtin_amdgcn_mfma_f32_16x16x32_bf16(a01, b11, acc01, 0, 0, 0);
    acc10 = __builtin_amdgcn_mfma_f32_16x16x32_bf16(a11, b01, acc10, 0, 0, 0);
    acc11 = __builtin_amdgcn_mfma_f32_16x16x32_bf16(a11, b11, acc11, 0, 0, 0);
    __syncthreads();  // drains vmcnt (prefetch landed) + all waves done
  }
#define STORE_FRAG(av, mi, ni)                                     \
  {                                                                \
    int rb = m0 + wr * 32 + (mi) * 16 + h * 4;                     \
    int col = n0 + wc * 32 + (ni) * 16 + c16;                      \
    out[(size_t)(rb + 0) * N_DIM + col] = av[0];                   \
    out[(size_t)(rb + 1) * N_DIM + col] = av[1];                   \
    out[(size_t)(rb + 2) * N_DIM + col] = av[2];                   \
    out[(size_t)(rb + 3) * N_DIM + col] = av[3];                   \
  }
  STORE_FRAG(acc00, 0, 0)
  STORE_FRAG(acc01, 0, 1)
  STORE_FRAG(acc10, 1, 0)
  STORE_FRAG(acc11, 1, 1)
#undef STORE_FRAG
#undef STAGE
}

// ---------------------------------------------------------------------------
// Launch
// ---------------------------------------------------------------------------
extern "C" void kernel_launch(void* const* d_in, const int* in_sizes, int n_in,
                              void* d_out, int out_size, void* d_ws,
                              size_t ws_size, hipStream_t stream) {
  const float* x = (const float*)d_in[0];    // (C, N)
  const float* W = (const float*)d_in[1];    // (O, C)
  const float* eps = (const float*)d_in[2];  // (C, N)
  float* out = (float*)d_out;                // (O, N)
  char* ws = (char*)d_ws;

  double* s_d = (double*)(ws + 0);                          //   8 KB
  double* part = (double*)(ws + 8192);                      // 512 KB
  int* idxo = (int*)(ws + 532480);                          //  80 KB
  float* xT = (float*)(ws + 614400);                        //   4 MB
  float* gT = (float*)(ws + 4808704);                       //   4 MB
  float* partials = (float*)(ws + 9003008);                 //  32 MB
  unsigned short* Acat = (unsigned short*)(ws + 42557440);  //  12 MB
  unsigned short* Bcat = (unsigned short*)(ws + 55140352);  //   6 MB

  norms_partial_kernel<<<dim3(4, 64), 256, 0, stream>>>(x, part);
  norms_reduce_kernel<<<4, 256, 0, stream>>>(part, s_d);

  // dot products: fp32, symmetric, split-K=8
  gemm64_sym<128><<<dim3(16, 16, NZ), 256, 0, stream>>>(x, partials);

  // independent prep (fills stream while dist results settle)
  fused_transpose<<<dim3(32, 32), 256, 0, stream>>>(x, eps, xT, gT);
  conv_w<<<1024, 256, 0, stream>>>(W, Acat);

  topk_kernel<<<N_DIM, 64, 0, stream>>>(partials, s_d, idxo);

  gather_bcat<<<N_DIM, 128, 0, stream>>>(xT, gT, idxo, Bcat);

  // out = W @ h via bf16 MFMA, grid 256 (XCD-swizzled internally)
  mfma_gemm<<<256, 512, 0, stream>>>(Acat, Bcat, out);
}

// Round 7
// 164.010 us; speedup vs baseline: 1.3324x; 1.0616x over previous
//
#include <hip/hip_runtime.h>

#define C_DIM 1024
#define N_DIM 1024
#define O_DIM 2048
#define K_NN  20
#define KCAT  3072  // 3 * 1024: [Whi,Whi,Wlo] x [hhi,hlo,hhi]
#define NZ    8     // dist GEMM split-K factor

typedef __attribute__((ext_vector_type(8))) short bf16x8;
typedef __attribute__((ext_vector_type(4))) float f32x4;

__device__ __forceinline__ unsigned short f2bf(float f) {
  unsigned u = __float_as_uint(f);
  unsigned r = (u + 0x7fffu + ((u >> 16) & 1u)) >> 16;  // RNE
  return (unsigned short)r;
}
__device__ __forceinline__ float bf2f(unsigned short h) {
  return __uint_as_float((unsigned)h << 16);
}

#define GLOAD16(gp, lp)                                                       \
  __builtin_amdgcn_global_load_lds(                                           \
      (const __attribute__((address_space(1))) unsigned int*)(uintptr_t)(gp), \
      (__attribute__((address_space(3))) unsigned int*)(uintptr_t)(lp), 16,   \
      0, 0)

// ---------------------------------------------------------------------------
// PREP (role-split, one launch): blocks [0,1024) transpose x/eps -> xT,gT;
// [1024,2048) conv W -> Acat; [2048,2304) norms partials (fp64).
// All roles independent; bodies bitwise-identical to round-5 kernels.
// ---------------------------------------------------------------------------
__global__ __launch_bounds__(256) void prep_kernel(
    const float* __restrict__ x, const float* __restrict__ eps,
    const float* __restrict__ W, float* __restrict__ xT,
    float* __restrict__ gT, unsigned short* __restrict__ Acat,
    double* __restrict__ part) {
  int b = blockIdx.x;
  int t = threadIdx.x;
  if (b < 1024) {
    // --- transpose role: x,eps (C,N) -> xT (N,C), gT = (1+eps)*x ---
    __shared__ float tx_[32][33], tg_[32][33];
    int bx = (b & 31) * 32, by = (b >> 5) * 32;
    int c = t & 31, r = t >> 5;
#pragma unroll
    for (int rr = 0; rr < 4; ++rr) {
      int row = by + r + 8 * rr;
      float xv = x[(size_t)row * N_DIM + bx + c];
      float ev = eps[(size_t)row * N_DIM + bx + c];
      tx_[r + 8 * rr][c] = xv;
      tg_[r + 8 * rr][c] = (1.f + ev) * xv;
    }
    __syncthreads();
#pragma unroll
    for (int rr = 0; rr < 4; ++rr) {
      xT[(size_t)(bx + r + 8 * rr) * C_DIM + by + c] = tx_[c][r + 8 * rr];
      gT[(size_t)(bx + r + 8 * rr) * C_DIM + by + c] = tg_[c][r + 8 * rr];
    }
  } else if (b < 2048) {
    // --- conv_w role: W (O,C) -> Acat segs hi,hi,lo; swizzled ---
    int id = (b - 1024) * 256 + t;
    int m = id >> 7;
    int gh = id & 127;
    int g = gh >> 2, h = gh & 3;
    int c1 = g * 32 + h * 4;
    const float* wp = &W[(size_t)m * C_DIM];
    float4 v1 = *(const float4*)&wp[c1];
    float4 v2 = *(const float4*)&wp[c1 + 16];
    float vv[8] = {v1.x, v1.y, v1.z, v1.w, v2.x, v2.y, v2.z, v2.w};
    unsigned hi[8], lo[8];
#pragma unroll
    for (int i = 0; i < 8; ++i) {
      unsigned short hb = f2bf(vv[i]);
      hi[i] = hb;
      lo[i] = f2bf(vv[i] - bf2f(hb));
    }
    uint4 ph, pl;
    ph.x = hi[0] | (hi[1] << 16); ph.y = hi[2] | (hi[3] << 16);
    ph.z = hi[4] | (hi[5] << 16); ph.w = hi[6] | (hi[7] << 16);
    pl.x = lo[0] | (lo[1] << 16); pl.y = lo[2] | (lo[3] << 16);
    pl.z = lo[4] | (lo[5] << 16); pl.w = lo[6] | (lo[7] << 16);
    int s = g >> 1;
    int pc = ((g & 1) * 4 + h) ^ (m & 7);
    unsigned short* row = Acat + (size_t)m * KCAT;
    *(uint4*)(row + s * 64 + pc * 8) = ph;
    *(uint4*)(row + 1024 + s * 64 + pc * 8) = ph;
    *(uint4*)(row + 2048 + s * 64 + pc * 8) = pl;
  } else {
    // --- norms partial role: 256 blocks, fp64, same order as round 5 ---
    int b2 = b - 2048;
    int j = (b2 & 3) * 256 + t;
    int cb = b2 >> 2;  // 0..63
    double acc = 0.0;
    int c0 = cb * 16;
#pragma unroll
    for (int c = c0; c < c0 + 16; ++c) {
      float v = x[(size_t)c * N_DIM + j];
      acc = fma((double)v, (double)v, acc);
    }
    part[(size_t)cb * N_DIM + j] = acc;
  }
}

// ---------------------------------------------------------------------------
// DIST (role-split): blocks [0,2048) = fp32 sym split-K GEMM (dot = x^T x),
// blocks [2048,2052) = norms reduce (part -> s_d). GEMM body identical to
// round-5 gemm64_sym<128>; mapping z = b>>8, bx = (b>>4)&15, by = b&15.
// ---------------------------------------------------------------------------
__global__ __launch_bounds__(256) void dist_kernel(
    const float* __restrict__ A, float* __restrict__ P,
    const double* __restrict__ part, double* __restrict__ s_d) {
  int b = blockIdx.x;
  int t = threadIdx.x;
  if (b >= 2048) {
    int j = (b - 2048) * 256 + t;
    double a = 0.0;
#pragma unroll
    for (int cb = 0; cb < 64; ++cb) a += part[(size_t)cb * N_DIM + j];
    s_d[j] = a;
    return;
  }
  const int KZ = 128;
  int z = b >> 8;
  int bx = (b >> 4) & 15, by = b & 15;
  if (by > bx) return;  // upper triangle only (uniform early return)
  __shared__ float Al[16][64];
  __shared__ float Bl[16][64];
  int tx = t & 15, ty = t >> 4;
  int m0 = by * 64, n0 = bx * 64;
  int kk = t >> 4, c4 = (t & 15) * 4;
  float acc[4][4] = {};
  for (int k0 = z * KZ; k0 < (z + 1) * KZ; k0 += 16) {
    float4 av = *(const float4*)&A[(size_t)(k0 + kk) * N_DIM + m0 + c4];
    float4 bv = *(const float4*)&A[(size_t)(k0 + kk) * N_DIM + n0 + c4];
    __syncthreads();
    *(float4*)&Al[kk][c4] = av;
    *(float4*)&Bl[kk][c4] = bv;
    __syncthreads();
#pragma unroll
    for (int q = 0; q < 16; ++q) {
      float4 a = *(const float4*)&Al[q][ty * 4];
      float4 bq = *(const float4*)&Bl[q][tx * 4];
      float am[4] = {a.x, a.y, a.z, a.w};
      float bn[4] = {bq.x, bq.y, bq.z, bq.w};
#pragma unroll
      for (int i = 0; i < 4; ++i)
#pragma unroll
        for (int j = 0; j < 4; ++j)
          acc[i][j] = fmaf(am[i], bn[j], acc[i][j]);
    }
  }
#pragma unroll
  for (int i = 0; i < 4; ++i) {
    float4 v = make_float4(acc[i][0], acc[i][1], acc[i][2], acc[i][3]);
    *(float4*)&P[((size_t)z * N_DIM + m0 + ty * 4 + i) * N_DIM + n0 + tx * 4] = v;
  }
  if (bx != by) {  // mirror (products commutative -> bitwise identical)
#pragma unroll
    for (int j = 0; j < 4; ++j) {
      float4 v = make_float4(acc[0][j], acc[1][j], acc[2][j], acc[3][j]);
      *(float4*)&P[((size_t)z * N_DIM + n0 + tx * 4 + j) * N_DIM + m0 + ty * 4] = v;
    }
  }
}

// ---------------------------------------------------------------------------
// TOPK + GATHER fused: one block of 128 per row i. Wave 0 runs the round-5
// topk (identical compare/reduce order, fp64), idx handoff via LDS; then both
// waves gather neighbors + eps-residual and emit swizzled bf16 Bcat.
// ---------------------------------------------------------------------------
__global__ __launch_bounds__(128) void topk_gather_kernel(
    const float* __restrict__ P, const double* __restrict__ s_d,
    const float* __restrict__ xT, const float* __restrict__ gT,
    unsigned short* __restrict__ Bcat) {
  __shared__ int sidx[K_NN];
  int i = blockIdx.x;
  int t = threadIdx.x;
  if (t < 64) {
    int l = t;
    double d[16];
#pragma unroll
    for (int q = 0; q < 16; ++q) {
      int j = q * 64 + l;
      double s = 0.0;
#pragma unroll
      for (int z = 0; z < NZ; ++z)
        s += (double)P[((size_t)z * N_DIM + i) * N_DIM + j];
      d[q] = 2.0 * s - s_d[j];
    }
    for (int r = 0; r < K_NN; ++r) {
      double bv = -1e300;
      int bj = N_DIM;
#pragma unroll
      for (int q = 0; q < 16; ++q) {
        int j = q * 64 + l;
        if (d[q] > bv) { bv = d[q]; bj = j; }
      }
#pragma unroll
      for (int off = 32; off; off >>= 1) {
        double ov = __shfl_xor(bv, off);
        int oj = __shfl_xor(bj, off);
        if (ov > bv || (ov == bv && oj < bj)) { bv = ov; bj = oj; }
      }
      if (l == 0) sidx[r] = bj;
      int kq = bj >> 6, kl = bj & 63;
      if (l == kl) {
#pragma unroll
        for (int q = 0; q < 16; ++q)
          if (q == kq) d[q] = -1e300;
      }
    }
  }
  __syncthreads();
  // --- gather role (identical arithmetic to round-5 gather_bcat) ---
  int n = i;
  int g = t >> 2, h = t & 3;
  int c1 = g * 32 + h * 4;
  int nb[K_NN];
#pragma unroll
  for (int k = 0; k < K_NN; ++k) nb[k] = sidx[k];
  float4 s1 = *(const float4*)&gT[(size_t)n * C_DIM + c1];
  float4 s2 = *(const float4*)&gT[(size_t)n * C_DIM + c1 + 16];
#pragma unroll
  for (int k = 0; k < K_NN; ++k) {
    const float* rp = &xT[(size_t)nb[k] * C_DIM];
    float4 v1 = *(const float4*)&rp[c1];
    float4 v2 = *(const float4*)&rp[c1 + 16];
    s1.x += v1.x; s1.y += v1.y; s1.z += v1.z; s1.w += v1.w;
    s2.x += v2.x; s2.y += v2.y; s2.z += v2.z; s2.w += v2.w;
  }
  float vv[8] = {s1.x, s1.y, s1.z, s1.w, s2.x, s2.y, s2.z, s2.w};
  unsigned hi[8], lo[8];
#pragma unroll
  for (int i2 = 0; i2 < 8; ++i2) {
    unsigned short hb = f2bf(vv[i2]);
    hi[i2] = hb;
    lo[i2] = f2bf(vv[i2] - bf2f(hb));
  }
  uint4 ph, pl;
  ph.x = hi[0] | (hi[1] << 16); ph.y = hi[2] | (hi[3] << 16);
  ph.z = hi[4] | (hi[5] << 16); ph.w = hi[6] | (hi[7] << 16);
  pl.x = lo[0] | (lo[1] << 16); pl.y = lo[2] | (lo[3] << 16);
  pl.z = lo[4] | (lo[5] << 16); pl.w = lo[6] | (lo[7] << 16);
  int s = g >> 1;
  int pc = ((g & 1) * 4 + h) ^ (n & 7);
  unsigned short* row = Bcat + (size_t)n * KCAT;
  *(uint4*)(row + s * 64 + pc * 8) = ph;
  *(uint4*)(row + 1024 + s * 64 + pc * 8) = pl;
  *(uint4*)(row + 2048 + s * 64 + pc * 8) = ph;
}

// ---------------------------------------------------------------------------
// bf16 MFMA GEMM: out (2048 x 1024) = Acat (2048 x 3072) x Bcat^T (1024 x 3072)
// 128x64 tile, 8 waves (4m x 2n, wave = 32x32), BK=64, dual-buffered LDS
// prefetch, 8-chunk XOR swizzle (2-way LDS reads = free), XCD-aware swizzle.
// ---------------------------------------------------------------------------
__global__ __launch_bounds__(512) void mfma_gemm(
    const unsigned short* __restrict__ Acat,
    const unsigned short* __restrict__ Bcat, float* __restrict__ out) {
  __shared__ unsigned short Alds[2][8192];  // [buf][128 rows x 64 k] 16KB each
  __shared__ unsigned short Blds[2][4096];  // [buf][ 64 rows x 64 k]  8KB each
  int t = threadIdx.x;
  int w = t >> 6, l = t & 63;
  int b = blockIdx.x;
  int xcd = b & 7, jb = b >> 3;
  int bx = xcd * 2 + (jb & 1);  // n-tile: 2 B-panels per XCD (L2-resident)
  int by = jb >> 1;             // m-tile
  int m0 = by * 128, n0 = bx * 64;
  int wr = w >> 1, wc = w & 1;
  int h = l >> 4, c16 = l & 15;
  int s8 = c16 & 7;

  const char* gA = (const char*)Acat + (size_t)(m0 + (t >> 3)) * (KCAT * 2) +
                   (t & 7) * 16;
  const char* gB = (const char*)Bcat + (size_t)(n0 + (t >> 3)) * (KCAT * 2) +
                   (t & 7) * 16;

  int ao00 = (wr * 32 + 0 + c16) * 64 + (((0 + h) ^ s8) * 8);
  int ao01 = (wr * 32 + 0 + c16) * 64 + (((4 + h) ^ s8) * 8);
  int ao10 = (wr * 32 + 16 + c16) * 64 + (((0 + h) ^ s8) * 8);
  int ao11 = (wr * 32 + 16 + c16) * 64 + (((4 + h) ^ s8) * 8);
  int bo00 = (wc * 32 + 0 + c16) * 64 + (((0 + h) ^ s8) * 8);
  int bo01 = (wc * 32 + 0 + c16) * 64 + (((4 + h) ^ s8) * 8);
  int bo10 = (wc * 32 + 16 + c16) * 64 + (((0 + h) ^ s8) * 8);
  int bo11 = (wc * 32 + 16 + c16) * 64 + (((4 + h) ^ s8) * 8);

  f32x4 acc00 = {}, acc01 = {}, acc10 = {}, acc11 = {};

#define STAGE(buf, it)                                                    \
  {                                                                       \
    const char* ga = gA + (size_t)(it) * 128;                             \
    const char* gb = gB + (size_t)(it) * 128;                             \
    GLOAD16(ga, (char*)&Alds[buf][0] + t * 16);                           \
    GLOAD16(ga + (size_t)64 * (KCAT * 2),                                 \
            (char*)&Alds[buf][0] + 8192 + t * 16);                        \
    GLOAD16(gb, (char*)&Blds[buf][0] + t * 16);                           \
  }

  STAGE(0, 0);
  __syncthreads();
  for (int it = 0; it < KCAT / 64; ++it) {
    int cur = it & 1;
    if (it + 1 < KCAT / 64) STAGE(cur ^ 1, it + 1);  // prefetch next slab
    const unsigned short* Ab = &Alds[cur][0];
    const unsigned short* Bb = &Blds[cur][0];
    bf16x8 a00 = *(const bf16x8*)(Ab + ao00);
    bf16x8 a10 = *(const bf16x8*)(Ab + ao10);
    bf16x8 b00 = *(const bf16x8*)(Bb + bo00);
    bf16x8 b10 = *(const bf16x8*)(Bb + bo10);
    acc00 = __builtin_amdgcn_mfma_f32_16x16x32_bf16(a00, b00, acc00, 0, 0, 0);
    acc01 = __builtin_amdgcn_mfma_f32_16x16x32_bf16(a00, b10, acc01, 0, 0, 0);
    acc10 = __builtin_amdgcn_mfma_f32_16x16x32_bf16(a10, b00, acc10, 0, 0, 0);
    acc11 = __builtin_amdgcn_mfma_f32_16x16x32_bf16(a10, b10, acc11, 0, 0, 0);
    bf16x8 a01 = *(const bf16x8*)(Ab + ao01);
    bf16x8 a11 = *(const bf16x8*)(Ab + ao11);
    bf16x8 b01 = *(const bf16x8*)(Bb + bo01);
    bf16x8 b11 = *(const bf16x8*)(Bb + bo11);
    acc00 = __builtin_amdgcn_mfma_f32_16x16x32_bf16(a01, b01, acc00, 0, 0, 0);
    acc01 = __builtin_amdgcn_mfma_f32_16x16x32_bf16(a01, b11, acc01, 0, 0, 0);
    acc10 = __builtin_amdgcn_mfma_f32_16x16x32_bf16(a11, b01, acc10, 0, 0, 0);
    acc11 = __builtin_amdgcn_mfma_f32_16x16x32_bf16(a11, b11, acc11, 0, 0, 0);
    __syncthreads();  // drains vmcnt (prefetch landed) + all waves done
  }
#define STORE_FRAG(av, mi, ni)                                     \
  {                                                                \
    int rb = m0 + wr * 32 + (mi) * 16 + h * 4;                     \
    int col = n0 + wc * 32 + (ni) * 16 + c16;                      \
    out[(size_t)(rb + 0) * N_DIM + col] = av[0];                   \
    out[(size_t)(rb + 1) * N_DIM + col] = av[1];                   \
    out[(size_t)(rb + 2) * N_DIM + col] = av[2];                   \
    out[(size_t)(rb + 3) * N_DIM + col] = av[3];                   \
  }
  STORE_FRAG(acc00, 0, 0)
  STORE_FRAG(acc01, 0, 1)
  STORE_FRAG(acc10, 1, 0)
  STORE_FRAG(acc11, 1, 1)
#undef STORE_FRAG
#undef STAGE
}

// ---------------------------------------------------------------------------
// Launch: 4 kernels (was 9).
// ---------------------------------------------------------------------------
extern "C" void kernel_launch(void* const* d_in, const int* in_sizes, int n_in,
                              void* d_out, int out_size, void* d_ws,
                              size_t ws_size, hipStream_t stream) {
  const float* x = (const float*)d_in[0];    // (C, N)
  const float* W = (const float*)d_in[1];    // (O, C)
  const float* eps = (const float*)d_in[2];  // (C, N)
  float* out = (float*)d_out;                // (O, N)
  char* ws = (char*)d_ws;

  double* s_d = (double*)(ws + 0);                          //   8 KB
  double* part = (double*)(ws + 8192);                      // 512 KB
  float* xT = (float*)(ws + 532480);                        //   4 MB
  float* gT = (float*)(ws + 4726784);                       //   4 MB
  float* partials = (float*)(ws + 8921088);                 //  32 MB
  unsigned short* Acat = (unsigned short*)(ws + 42475520);  //  12 MB
  unsigned short* Bcat = (unsigned short*)(ws + 55058432);  //   6 MB

  // 1: transpose + conv_w + norms partials (independent roles, one launch)
  prep_kernel<<<2304, 256, 0, stream>>>(x, eps, W, xT, gT, Acat, part);

  // 2: dist dot-products (fp32 sym split-K=8) + norms reduce
  dist_kernel<<<2052, 256, 0, stream>>>(x, partials, part, s_d);

  // 3: top-20 + gather + Bcat build (idx via LDS)
  topk_gather_kernel<<<1024, 128, 0, stream>>>(partials, s_d, xT, gT, Bcat);

  // 4: out = W @ h via bf16 MFMA
  mfma_gemm<<<256, 512, 0, stream>>>(Acat, Bcat, out);
}

// Round 8
// 152.768 us; speedup vs baseline: 1.4304x; 1.0736x over previous
//
#include <hip/hip_runtime.h>

#define C_DIM 1024
#define N_DIM 1024
#define O_DIM 2048
#define K_NN  20
#define KCAT  3072  // 3 * 1024: [Whi,Whi,Wlo] x [hhi,hlo,hhi]
#define NZ    8     // dist GEMM split-K factor

typedef __attribute__((ext_vector_type(8))) short bf16x8;
typedef __attribute__((ext_vector_type(4))) float f32x4;

__device__ __forceinline__ unsigned short f2bf(float f) {
  unsigned u = __float_as_uint(f);
  unsigned r = (u + 0x7fffu + ((u >> 16) & 1u)) >> 16;  // RNE
  return (unsigned short)r;
}
__device__ __forceinline__ float bf2f(unsigned short h) {
  return __uint_as_float((unsigned)h << 16);
}

#define GLOAD16(gp, lp)                                                       \
  __builtin_amdgcn_global_load_lds(                                           \
      (const __attribute__((address_space(1))) unsigned int*)(uintptr_t)(gp), \
      (__attribute__((address_space(3))) unsigned int*)(uintptr_t)(lp), 16,   \
      0, 0)

// ---------------------------------------------------------------------------
// PREP (role-split, one launch): blocks [0,1024) transpose x/eps -> xT,gT;
// [1024,2048) conv W -> Acat; [2048,2304) norms partials (fp64).
// ---------------------------------------------------------------------------
__global__ __launch_bounds__(256) void prep_kernel(
    const float* __restrict__ x, const float* __restrict__ eps,
    const float* __restrict__ W, float* __restrict__ xT,
    float* __restrict__ gT, unsigned short* __restrict__ Acat,
    double* __restrict__ part) {
  int b = blockIdx.x;
  int t = threadIdx.x;
  if (b < 1024) {
    __shared__ float tx_[32][33], tg_[32][33];
    int bx = (b & 31) * 32, by = (b >> 5) * 32;
    int c = t & 31, r = t >> 5;
#pragma unroll
    for (int rr = 0; rr < 4; ++rr) {
      int row = by + r + 8 * rr;
      float xv = x[(size_t)row * N_DIM + bx + c];
      float ev = eps[(size_t)row * N_DIM + bx + c];
      tx_[r + 8 * rr][c] = xv;
      tg_[r + 8 * rr][c] = (1.f + ev) * xv;
    }
    __syncthreads();
#pragma unroll
    for (int rr = 0; rr < 4; ++rr) {
      xT[(size_t)(bx + r + 8 * rr) * C_DIM + by + c] = tx_[c][r + 8 * rr];
      gT[(size_t)(bx + r + 8 * rr) * C_DIM + by + c] = tg_[c][r + 8 * rr];
    }
  } else if (b < 2048) {
    int id = (b - 1024) * 256 + t;
    int m = id >> 7;
    int gh = id & 127;
    int g = gh >> 2, h = gh & 3;
    int c1 = g * 32 + h * 4;
    const float* wp = &W[(size_t)m * C_DIM];
    float4 v1 = *(const float4*)&wp[c1];
    float4 v2 = *(const float4*)&wp[c1 + 16];
    float vv[8] = {v1.x, v1.y, v1.z, v1.w, v2.x, v2.y, v2.z, v2.w};
    unsigned hi[8], lo[8];
#pragma unroll
    for (int i = 0; i < 8; ++i) {
      unsigned short hb = f2bf(vv[i]);
      hi[i] = hb;
      lo[i] = f2bf(vv[i] - bf2f(hb));
    }
    uint4 ph, pl;
    ph.x = hi[0] | (hi[1] << 16); ph.y = hi[2] | (hi[3] << 16);
    ph.z = hi[4] | (hi[5] << 16); ph.w = hi[6] | (hi[7] << 16);
    pl.x = lo[0] | (lo[1] << 16); pl.y = lo[2] | (lo[3] << 16);
    pl.z = lo[4] | (lo[5] << 16); pl.w = lo[6] | (lo[7] << 16);
    int s = g >> 1;
    int pc = ((g & 1) * 4 + h) ^ (m & 7);
    unsigned short* row = Acat + (size_t)m * KCAT;
    *(uint4*)(row + s * 64 + pc * 8) = ph;
    *(uint4*)(row + 1024 + s * 64 + pc * 8) = ph;
    *(uint4*)(row + 2048 + s * 64 + pc * 8) = pl;
  } else {
    int b2 = b - 2048;
    int j = (b2 & 3) * 256 + t;
    int cb = b2 >> 2;  // 0..63
    double acc = 0.0;
    int c0 = cb * 16;
#pragma unroll
    for (int c = c0; c < c0 + 16; ++c) {
      float v = x[(size_t)c * N_DIM + j];
      acc = fma((double)v, (double)v, acc);
    }
    part[(size_t)cb * N_DIM + j] = acc;
  }
}

// ---------------------------------------------------------------------------
// DIST: blocks [0,2048) = fp32 sym split-K GEMM, [2048,2052) = norms reduce.
// BK=32 (half the barriers of round 7) + register prefetch issued BEFORE the
// compute block so ~1024cyc of FMAs hide the global-load latency. Per-thread
// FMA order unchanged (k ascending) -> bitwise identical to round 7.
// ---------------------------------------------------------------------------
__global__ __launch_bounds__(256) void dist_kernel(
    const float* __restrict__ A, float* __restrict__ P,
    const double* __restrict__ part, double* __restrict__ s_d) {
  int b = blockIdx.x;
  int t = threadIdx.x;
  if (b >= 2048) {
    int j = (b - 2048) * 256 + t;
    double a = 0.0;
#pragma unroll
    for (int cb = 0; cb < 64; ++cb) a += part[(size_t)cb * N_DIM + j];
    s_d[j] = a;
    return;
  }
  const int KZ = 128;
  int z = b >> 8;
  int bx = (b >> 4) & 15, by = b & 15;
  if (by > bx) return;  // upper triangle only (uniform early return)
  __shared__ float Al[32][64];
  __shared__ float Bl[32][64];
  int tx = t & 15, ty = t >> 4;
  int m0 = by * 64, n0 = bx * 64;
  int kk = t >> 4, c4 = (t & 15) * 4;
  float acc[4][4] = {};
  int k0 = z * KZ;
  // prologue prefetch (tile 0)
  float4 a0 = *(const float4*)&A[(size_t)(k0 + kk) * N_DIM + m0 + c4];
  float4 a1 = *(const float4*)&A[(size_t)(k0 + kk + 16) * N_DIM + m0 + c4];
  float4 b0 = *(const float4*)&A[(size_t)(k0 + kk) * N_DIM + n0 + c4];
  float4 b1 = *(const float4*)&A[(size_t)(k0 + kk + 16) * N_DIM + n0 + c4];
  for (int kt = 0; kt < KZ / 32; ++kt) {
    __syncthreads();  // prev compute done; vmcnt drain -> regs landed
    *(float4*)&Al[kk][c4] = a0;
    *(float4*)&Al[kk + 16][c4] = a1;
    *(float4*)&Bl[kk][c4] = b0;
    *(float4*)&Bl[kk + 16][c4] = b1;
    __syncthreads();
    if (kt + 1 < KZ / 32) {  // issue next tile's loads before compute
      int kn = k0 + (kt + 1) * 32;
      a0 = *(const float4*)&A[(size_t)(kn + kk) * N_DIM + m0 + c4];
      a1 = *(const float4*)&A[(size_t)(kn + kk + 16) * N_DIM + m0 + c4];
      b0 = *(const float4*)&A[(size_t)(kn + kk) * N_DIM + n0 + c4];
      b1 = *(const float4*)&A[(size_t)(kn + kk + 16) * N_DIM + n0 + c4];
    }
#pragma unroll
    for (int q = 0; q < 32; ++q) {
      float4 a = *(const float4*)&Al[q][ty * 4];
      float4 bq = *(const float4*)&Bl[q][tx * 4];
      float am[4] = {a.x, a.y, a.z, a.w};
      float bn[4] = {bq.x, bq.y, bq.z, bq.w};
#pragma unroll
      for (int i = 0; i < 4; ++i)
#pragma unroll
        for (int j = 0; j < 4; ++j)
          acc[i][j] = fmaf(am[i], bn[j], acc[i][j]);
    }
  }
#pragma unroll
  for (int i = 0; i < 4; ++i) {
    float4 v = make_float4(acc[i][0], acc[i][1], acc[i][2], acc[i][3]);
    *(float4*)&P[((size_t)z * N_DIM + m0 + ty * 4 + i) * N_DIM + n0 + tx * 4] = v;
  }
  if (bx != by) {  // mirror (products commutative -> bitwise identical)
#pragma unroll
    for (int j = 0; j < 4; ++j) {
      float4 v = make_float4(acc[0][j], acc[1][j], acc[2][j], acc[3][j]);
      *(float4*)&P[((size_t)z * N_DIM + n0 + tx * 4 + j) * N_DIM + m0 + ty * 4] = v;
    }
  }
}

// ---------------------------------------------------------------------------
// TOPK + GATHER fused (unchanged from round 7).
// ---------------------------------------------------------------------------
__global__ __launch_bounds__(128) void topk_gather_kernel(
    const float* __restrict__ P, const double* __restrict__ s_d,
    const float* __restrict__ xT, const float* __restrict__ gT,
    unsigned short* __restrict__ Bcat) {
  __shared__ int sidx[K_NN];
  int i = blockIdx.x;
  int t = threadIdx.x;
  if (t < 64) {
    int l = t;
    double d[16];
#pragma unroll
    for (int q = 0; q < 16; ++q) {
      int j = q * 64 + l;
      double s = 0.0;
#pragma unroll
      for (int z = 0; z < NZ; ++z)
        s += (double)P[((size_t)z * N_DIM + i) * N_DIM + j];
      d[q] = 2.0 * s - s_d[j];
    }
    for (int r = 0; r < K_NN; ++r) {
      double bv = -1e300;
      int bj = N_DIM;
#pragma unroll
      for (int q = 0; q < 16; ++q) {
        int j = q * 64 + l;
        if (d[q] > bv) { bv = d[q]; bj = j; }
      }
#pragma unroll
      for (int off = 32; off; off >>= 1) {
        double ov = __shfl_xor(bv, off);
        int oj = __shfl_xor(bj, off);
        if (ov > bv || (ov == bv && oj < bj)) { bv = ov; bj = oj; }
      }
      if (l == 0) sidx[r] = bj;
      int kq = bj >> 6, kl = bj & 63;
      if (l == kl) {
#pragma unroll
        for (int q = 0; q < 16; ++q)
          if (q == kq) d[q] = -1e300;
      }
    }
  }
  __syncthreads();
  int n = i;
  int g = t >> 2, h = t & 3;
  int c1 = g * 32 + h * 4;
  int nb[K_NN];
#pragma unroll
  for (int k = 0; k < K_NN; ++k) nb[k] = sidx[k];
  float4 s1 = *(const float4*)&gT[(size_t)n * C_DIM + c1];
  float4 s2 = *(const float4*)&gT[(size_t)n * C_DIM + c1 + 16];
#pragma unroll
  for (int k = 0; k < K_NN; ++k) {
    const float* rp = &xT[(size_t)nb[k] * C_DIM];
    float4 v1 = *(const float4*)&rp[c1];
    float4 v2 = *(const float4*)&rp[c1 + 16];
    s1.x += v1.x; s1.y += v1.y; s1.z += v1.z; s1.w += v1.w;
    s2.x += v2.x; s2.y += v2.y; s2.z += v2.z; s2.w += v2.w;
  }
  float vv[8] = {s1.x, s1.y, s1.z, s1.w, s2.x, s2.y, s2.z, s2.w};
  unsigned hi[8], lo[8];
#pragma unroll
  for (int i2 = 0; i2 < 8; ++i2) {
    unsigned short hb = f2bf(vv[i2]);
    hi[i2] = hb;
    lo[i2] = f2bf(vv[i2] - bf2f(hb));
  }
  uint4 ph, pl;
  ph.x = hi[0] | (hi[1] << 16); ph.y = hi[2] | (hi[3] << 16);
  ph.z = hi[4] | (hi[5] << 16); ph.w = hi[6] | (hi[7] << 16);
  pl.x = lo[0] | (lo[1] << 16); pl.y = lo[2] | (lo[3] << 16);
  pl.z = lo[4] | (lo[5] << 16); pl.w = lo[6] | (lo[7] << 16);
  int s = g >> 1;
  int pc = ((g & 1) * 4 + h) ^ (n & 7);
  unsigned short* row = Bcat + (size_t)n * KCAT;
  *(uint4*)(row + s * 64 + pc * 8) = ph;
  *(uint4*)(row + 1024 + s * 64 + pc * 8) = pl;
  *(uint4*)(row + 2048 + s * 64 + pc * 8) = ph;
}

// ---------------------------------------------------------------------------
// bf16 MFMA GEMM, now T4-style: 3 LDS buffers, 2-ahead global_load_lds
// prefetch, counted s_waitcnt vmcnt(3) + raw s_barrier + sched_barrier(0)
// (one barrier per K-step; loads stay in flight across barriers).
// MFMA order/data identical to round 7 -> bitwise-identical output.
// ---------------------------------------------------------------------------
__global__ __launch_bounds__(512) void mfma_gemm(
    const unsigned short* __restrict__ Acat,
    const unsigned short* __restrict__ Bcat, float* __restrict__ out) {
  __shared__ unsigned short Alds[3][8192];  // 3 x 16KB (128 rows x 64 k)
  __shared__ unsigned short Blds[3][4096];  // 3 x  8KB ( 64 rows x 64 k)
  int t = threadIdx.x;
  int w = t >> 6, l = t & 63;
  int b = blockIdx.x;
  int xcd = b & 7, jb = b >> 3;
  int bx = xcd * 2 + (jb & 1);
  int by = jb >> 1;
  int m0 = by * 128, n0 = bx * 64;
  int wr = w >> 1, wc = w & 1;
  int h = l >> 4, c16 = l & 15;
  int s8 = c16 & 7;

  const char* gA = (const char*)Acat + (size_t)(m0 + (t >> 3)) * (KCAT * 2) +
                   (t & 7) * 16;
  const char* gB = (const char*)Bcat + (size_t)(n0 + (t >> 3)) * (KCAT * 2) +
                   (t & 7) * 16;

  int ao00 = (wr * 32 + 0 + c16) * 64 + (((0 + h) ^ s8) * 8);
  int ao01 = (wr * 32 + 0 + c16) * 64 + (((4 + h) ^ s8) * 8);
  int ao10 = (wr * 32 + 16 + c16) * 64 + (((0 + h) ^ s8) * 8);
  int ao11 = (wr * 32 + 16 + c16) * 64 + (((4 + h) ^ s8) * 8);
  int bo00 = (wc * 32 + 0 + c16) * 64 + (((0 + h) ^ s8) * 8);
  int bo01 = (wc * 32 + 0 + c16) * 64 + (((4 + h) ^ s8) * 8);
  int bo10 = (wc * 32 + 16 + c16) * 64 + (((0 + h) ^ s8) * 8);
  int bo11 = (wc * 32 + 16 + c16) * 64 + (((4 + h) ^ s8) * 8);

  f32x4 acc00 = {}, acc01 = {}, acc10 = {}, acc11 = {};

#define STAGE3(bufi, itv)                                                 \
  {                                                                       \
    const char* ga = gA + (size_t)(itv) * 128;                            \
    const char* gb = gB + (size_t)(itv) * 128;                            \
    GLOAD16(ga, (char*)&Alds[bufi][0] + t * 16);                          \
    GLOAD16(ga + (size_t)64 * (KCAT * 2),                                 \
            (char*)&Alds[bufi][0] + 8192 + t * 16);                       \
    GLOAD16(gb, (char*)&Blds[bufi][0] + t * 16);                          \
  }

#define COMPUTE(bufi)                                                         \
  {                                                                           \
    const unsigned short* Ab = &Alds[bufi][0];                                \
    const unsigned short* Bb = &Blds[bufi][0];                                \
    bf16x8 a00 = *(const bf16x8*)(Ab + ao00);                                 \
    bf16x8 a10 = *(const bf16x8*)(Ab + ao10);                                 \
    bf16x8 b00 = *(const bf16x8*)(Bb + bo00);                                 \
    bf16x8 b10 = *(const bf16x8*)(Bb + bo10);                                 \
    acc00 = __builtin_amdgcn_mfma_f32_16x16x32_bf16(a00, b00, acc00, 0, 0, 0);\
    acc01 = __builtin_amdgcn_mfma_f32_16x16x32_bf16(a00, b10, acc01, 0, 0, 0);\
    acc10 = __builtin_amdgcn_mfma_f32_16x16x32_bf16(a10, b00, acc10, 0, 0, 0);\
    acc11 = __builtin_amdgcn_mfma_f32_16x16x32_bf16(a10, b10, acc11, 0, 0, 0);\
    bf16x8 a01 = *(const bf16x8*)(Ab + ao01);                                 \
    bf16x8 a11 = *(const bf16x8*)(Ab + ao11);                                 \
    bf16x8 b01 = *(const bf16x8*)(Bb + bo01);                                 \
    bf16x8 b11 = *(const bf16x8*)(Bb + bo11);                                 \
    acc00 = __builtin_amdgcn_mfma_f32_16x16x32_bf16(a01, b01, acc00, 0, 0, 0);\
    acc01 = __builtin_amdgcn_mfma_f32_16x16x32_bf16(a01, b11, acc01, 0, 0, 0);\
    acc10 = __builtin_amdgcn_mfma_f32_16x16x32_bf16(a11, b01, acc10, 0, 0, 0);\
    acc11 = __builtin_amdgcn_mfma_f32_16x16x32_bf16(a11, b11, acc11, 0, 0, 0);\
  }

  const int NT = KCAT / 64;  // 48
  STAGE3(0, 0);
  STAGE3(1, 1);
  int cur = 0;
  for (int it = 0; it < NT - 1; ++it) {
    // own stage-it loads landed when <=3 outstanding (stage it+1 in flight)
    asm volatile("s_waitcnt vmcnt(3)" ::: "memory");
    __builtin_amdgcn_s_barrier();          // all waves' stage-it landed
    __builtin_amdgcn_sched_barrier(0);     // no ds_read hoisting above
    COMPUTE(cur);
    if (it < NT - 2) {
      int bs = cur + 2;
      if (bs >= 3) bs -= 3;
      STAGE3(bs, it + 2);                  // issued after barrier: WAR-safe
    }
    cur = (cur == 2) ? 0 : cur + 1;
  }
  asm volatile("s_waitcnt vmcnt(0)" ::: "memory");  // last stage
  __builtin_amdgcn_s_barrier();
  __builtin_amdgcn_sched_barrier(0);
  COMPUTE(cur);

#define STORE_FRAG(av, mi, ni)                                     \
  {                                                                \
    int rb = m0 + wr * 32 + (mi) * 16 + h * 4;                     \
    int col = n0 + wc * 32 + (ni) * 16 + c16;                      \
    out[(size_t)(rb + 0) * N_DIM + col] = av[0];                   \
    out[(size_t)(rb + 1) * N_DIM + col] = av[1];                   \
    out[(size_t)(rb + 2) * N_DIM + col] = av[2];                   \
    out[(size_t)(rb + 3) * N_DIM + col] = av[3];                   \
  }
  STORE_FRAG(acc00, 0, 0)
  STORE_FRAG(acc01, 0, 1)
  STORE_FRAG(acc10, 1, 0)
  STORE_FRAG(acc11, 1, 1)
#undef STORE_FRAG
#undef COMPUTE
#undef STAGE3
}

// ---------------------------------------------------------------------------
// Launch: 4 kernels.
// ---------------------------------------------------------------------------
extern "C" void kernel_launch(void* const* d_in, const int* in_sizes, int n_in,
                              void* d_out, int out_size, void* d_ws,
                              size_t ws_size, hipStream_t stream) {
  const float* x = (const float*)d_in[0];    // (C, N)
  const float* W = (const float*)d_in[1];    // (O, C)
  const float* eps = (const float*)d_in[2];  // (C, N)
  float* out = (float*)d_out;                // (O, N)
  char* ws = (char*)d_ws;

  double* s_d = (double*)(ws + 0);                          //   8 KB
  double* part = (double*)(ws + 8192);                      // 512 KB
  float* xT = (float*)(ws + 532480);                        //   4 MB
  float* gT = (float*)(ws + 4726784);                       //   4 MB
  float* partials = (float*)(ws + 8921088);                 //  32 MB
  unsigned short* Acat = (unsigned short*)(ws + 42475520);  //  12 MB
  unsigned short* Bcat = (unsigned short*)(ws + 55058432);  //   6 MB

  prep_kernel<<<2304, 256, 0, stream>>>(x, eps, W, xT, gT, Acat, part);
  dist_kernel<<<2052, 256, 0, stream>>>(x, partials, part, s_d);
  topk_gather_kernel<<<1024, 128, 0, stream>>>(partials, s_d, xT, gT, Bcat);
  mfma_gemm<<<256, 512, 0, stream>>>(Acat, Bcat, out);
}